// Round 1
// baseline (95.888 us; speedup 1.0000x reference)
//
#include <hip/hip_runtime.h>

// B rows; each input row: [tx, ty, tz, ax, ay, az] (f32)
// output row (12 f32): [M00-1, M01, M02, tx, M10, M11-1, M12, ty, M20, M21, M22-1, tz]
// where M = Rx(ax) @ Ry(ay) @ Rz(az), expanded in closed form.

__global__ __launch_bounds__(256) void affine_to_matrix_kernel(
    const float* __restrict__ in, float* __restrict__ out, int npairs) {
    int t = blockIdx.x * blockDim.x + threadIdx.x;
    if (t >= npairs) return;

    // Two rows per thread: 12 input floats = 3x float4 (16B aligned, 48B stride).
    const float4* ip = reinterpret_cast<const float4*>(in + (size_t)t * 12);
    float4 v0 = ip[0];
    float4 v1 = ip[1];
    float4 v2 = ip[2];

    float r[12];
    r[0] = v0.x; r[1] = v0.y; r[2]  = v0.z; r[3]  = v0.w;
    r[4] = v1.x; r[5] = v1.y; r[6]  = v1.z; r[7]  = v1.w;
    r[8] = v2.x; r[9] = v2.y; r[10] = v2.z; r[11] = v2.w;

    float o[24];
    #pragma unroll
    for (int k = 0; k < 2; ++k) {
        const float* v = r + k * 6;
        float tx = v[0], ty = v[1], tz = v[2];
        float sx, cx, sy, cy, sz, cz;
        __sincosf(v[3], &sx, &cx);
        __sincosf(v[4], &sy, &cy);
        __sincosf(v[5], &sz, &cz);

        float sxsy = sx * sy;
        float cxsy = cx * sy;

        float* m = o + k * 12;
        m[0]  = cy * cz - 1.0f;        // M00 - 1
        m[1]  = -cy * sz;              // M01
        m[2]  = sy;                    // M02
        m[3]  = tx;
        m[4]  = cx * sz + sxsy * cz;   // M10
        m[5]  = cx * cz - sxsy * sz - 1.0f; // M11 - 1
        m[6]  = -sx * cy;              // M12
        m[7]  = ty;
        m[8]  = sx * sz - cxsy * cz;   // M20
        m[9]  = sx * cz + cxsy * sz;   // M21
        m[10] = cx * cy - 1.0f;        // M22 - 1
        m[11] = tz;
    }

    // Two rows out: 24 floats = 6x float4 (16B aligned, 96B stride).
    float4* op = reinterpret_cast<float4*>(out + (size_t)t * 24);
    #pragma unroll
    for (int q = 0; q < 6; ++q) {
        op[q] = make_float4(o[q * 4 + 0], o[q * 4 + 1], o[q * 4 + 2], o[q * 4 + 3]);
    }
}

extern "C" void kernel_launch(void* const* d_in, const int* in_sizes, int n_in,
                              void* d_out, int out_size, void* d_ws, size_t ws_size,
                              hipStream_t stream) {
    const float* in = (const float*)d_in[0];
    float* out = (float*)d_out;
    int B = in_sizes[0] / 6;       // 4194304
    int npairs = B / 2;            // B is a power of two, evenly divisible
    int block = 256;
    int grid = (npairs + block - 1) / block;
    affine_to_matrix_kernel<<<grid, block, 0, stream>>>(in, out, npairs);
}

// Round 2
// 51.373 us; speedup vs baseline: 1.8665x; 1.8665x over previous
//
#include <hip/hip_runtime.h>

// B rows; input row: [tx, ty, tz, ax, ay, az] (f32)
// output row (12 f32): [M00-1, M01, M02, tx, M10, M11-1, M12, ty, M20, M21, M22-1, tz]
// where M = Rx(ax) @ Ry(ay) @ Rz(az), expanded in closed form.
//
// All global traffic is coalesced float4 via LDS staging:
//   phase 1: 3x float4/thread global->LDS (linear, conflict-free)
//   phase 2: per-thread row-pair read (b128, ~2-way = free), compute,
//            LDS write (b128 stride 96B, 4-way ~1.58x, hidden under VMEM)
//   phase 3: 6x float4/thread LDS->global (linear, conflict-free)

#define BLOCK 256
#define RPB   512   // rows per block (2 per thread)

__global__ __launch_bounds__(BLOCK) void affine_to_matrix_staged(
    const float* __restrict__ in, float* __restrict__ out) {
    __shared__ float s_in[RPB * 6];    // 12 KB
    __shared__ float s_out[RPB * 12];  // 24 KB

    const int tid = threadIdx.x;
    const size_t rowBase = (size_t)blockIdx.x * RPB;
    const float4* gin  = reinterpret_cast<const float4*>(in  + rowBase * 6);
    float4*       gout = reinterpret_cast<float4*>(out + rowBase * 12);

    // Phase 1: coalesced global -> LDS
    float4* s_in4 = reinterpret_cast<float4*>(s_in);
    #pragma unroll
    for (int k = 0; k < 3; ++k) {
        int g = tid + k * BLOCK;
        s_in4[g] = gin[g];
    }
    __syncthreads();

    // Phase 2: compute two rows per thread
    const float4* myin = reinterpret_cast<const float4*>(s_in + tid * 12);
    float4 a = myin[0], b = myin[1], c = myin[2];
    float r[12] = {a.x, a.y, a.z, a.w, b.x, b.y, b.z, b.w, c.x, c.y, c.z, c.w};
    float4* myout = reinterpret_cast<float4*>(s_out + tid * 24);
    #pragma unroll
    for (int k2 = 0; k2 < 2; ++k2) {
        const float* v = r + k2 * 6;
        float sx, cx, sy, cy, sz, cz;
        __sincosf(v[3], &sx, &cx);
        __sincosf(v[4], &sy, &cy);
        __sincosf(v[5], &sz, &cz);
        float sxsy = sx * sy;
        float cxsy = cx * sy;
        float m0 = cy * cz - 1.0f, m1 = -cy * sz,               m2  = sy;
        float m4 = cx * sz + sxsy * cz, m5 = cx * cz - sxsy * sz - 1.0f, m6 = -sx * cy;
        float m8 = sx * sz - cxsy * cz, m9 = sx * cz + cxsy * sz, m10 = cx * cy - 1.0f;
        myout[k2 * 3 + 0] = make_float4(m0, m1, m2,  v[0]);
        myout[k2 * 3 + 1] = make_float4(m4, m5, m6,  v[1]);
        myout[k2 * 3 + 2] = make_float4(m8, m9, m10, v[2]);
    }
    __syncthreads();

    // Phase 3: coalesced LDS -> global
    const float4* s_out4 = reinterpret_cast<const float4*>(s_out);
    #pragma unroll
    for (int k = 0; k < 6; ++k) {
        int g = tid + k * BLOCK;
        gout[g] = s_out4[g];
    }
}

// Tail path: one row per thread, no staging (only used if rows % RPB != 0).
__global__ __launch_bounds__(BLOCK) void affine_to_matrix_tail(
    const float* __restrict__ in, float* __restrict__ out,
    size_t rowStart, size_t nRows) {
    size_t i = rowStart + blockIdx.x * (size_t)BLOCK + threadIdx.x;
    if (i >= nRows) return;
    const float* v = in + i * 6;
    float tx = v[0], ty = v[1], tz = v[2];
    float sx, cx, sy, cy, sz, cz;
    __sincosf(v[3], &sx, &cx);
    __sincosf(v[4], &sy, &cy);
    __sincosf(v[5], &sz, &cz);
    float sxsy = sx * sy, cxsy = cx * sy;
    float* m = out + i * 12;
    m[0] = cy * cz - 1.0f;  m[1] = -cy * sz;                m[2]  = sy;             m[3]  = tx;
    m[4] = cx * sz + sxsy * cz; m[5] = cx * cz - sxsy * sz - 1.0f; m[6] = -sx * cy;  m[7]  = ty;
    m[8] = sx * sz - cxsy * cz; m[9] = sx * cz + cxsy * sz; m[10] = cx * cy - 1.0f;  m[11] = tz;
}

extern "C" void kernel_launch(void* const* d_in, const int* in_sizes, int n_in,
                              void* d_out, int out_size, void* d_ws, size_t ws_size,
                              hipStream_t stream) {
    const float* in = (const float*)d_in[0];
    float* out = (float*)d_out;
    size_t rows = (size_t)in_sizes[0] / 6;   // 4194304
    size_t fullBlocks = rows / RPB;          // 8192 (exact for this B)
    if (fullBlocks) {
        affine_to_matrix_staged<<<(unsigned)fullBlocks, BLOCK, 0, stream>>>(in, out);
    }
    size_t rem = rows - fullBlocks * RPB;
    if (rem) {
        unsigned tailGrid = (unsigned)((rem + BLOCK - 1) / BLOCK);
        affine_to_matrix_tail<<<tailGrid, BLOCK, 0, stream>>>(in, out, fullBlocks * RPB, rows);
    }
}